// Round 6
// baseline (2457.701 us; speedup 1.0000x reference)
//
#include <hip/hip_runtime.h>
#include <cstdint>
#include <cstddef>

#define BB 8
#define SS 2
#define TT 512
#define CC 2048
#define ND 1024
#define AD 16384
#define NN 256
#define AN 2048
#define APTD 10   // max arcs/thread in a den quarter (5120 cap vs ~4096 mean, ~18 sigma)

// ---------------------------------------------------------------------------
// agent-scope atomic helpers (cross-XCD safe exchange)
// ---------------------------------------------------------------------------
__device__ __forceinline__ void astore_f(float* p, float v) {
    __hip_atomic_store((unsigned int*)p, __float_as_uint(v),
                       __ATOMIC_RELAXED, __HIP_MEMORY_SCOPE_AGENT);
}
__device__ __forceinline__ unsigned long long aload_u64(const float* p) {
    return __hip_atomic_load((const unsigned long long*)p,
                             __ATOMIC_RELAXED, __HIP_MEMORY_SCOPE_AGENT);
}
__device__ __forceinline__ float u2f_lo(unsigned long long v) {
    return __uint_as_float((unsigned)v);
}
__device__ __forceinline__ float u2f_hi(unsigned long long v) {
    return __uint_as_float((unsigned)(v >> 32));
}

// ---------------------------------------------------------------------------
// prep: per-graph counting sort of arcs by dst. Record packs indices into one
// u32: src | pdf<<10 | dst<<21; payload .y = exp(weight). Optionally emits
// CSR rowptr (needed for the den dst-range partition).
// ---------------------------------------------------------------------------
__global__ void prep_kernel(const int* __restrict__ src, const int* __restrict__ dst,
                            const int* __restrict__ pdf, const float* __restrict__ w,
                            uint2* __restrict__ arcs, unsigned* __restrict__ rowptr,
                            int N, int A)
{
    __shared__ int cnt[1024];
    __shared__ int pos[1024];
    const int g = blockIdx.x;
    src += (size_t)g * A; dst += (size_t)g * A; pdf += (size_t)g * A; w += (size_t)g * A;
    arcs += (size_t)g * A;
    const int tid = threadIdx.x;
    cnt[tid] = 0;
    __syncthreads();
    for (int a = tid; a < A; a += blockDim.x) atomicAdd(&cnt[dst[a]], 1);
    __syncthreads();
    const int deg = cnt[tid];
    pos[tid] = deg;
    __syncthreads();
    for (int off = 1; off < blockDim.x; off <<= 1) {
        int add = (tid >= off) ? pos[tid - off] : 0;
        __syncthreads();
        pos[tid] += add;
        __syncthreads();
    }
    const int excl = pos[tid] - deg;
    if (rowptr) {
        rowptr[tid] = (unsigned)excl;
        if (tid == (int)blockDim.x - 1) rowptr[N] = (unsigned)A;
    }
    cnt[tid] = excl;
    __syncthreads();
    for (int a = tid; a < A; a += blockDim.x) {
        const int d2 = dst[a];
        const int p2 = atomicAdd(&cnt[d2], 1);
        arcs[p2] = make_uint2((unsigned)src[a] | ((unsigned)pdf[a] << 10) |
                              ((unsigned)d2 << 21),
                              __float_as_uint(__expf(w[a])));
    }
}

__global__ void zero_sync_kernel(unsigned* __restrict__ cnt)
{
    if (threadIdx.x < 16) cnt[threadIdx.x] = 0;
}

// ---------------------------------------------------------------------------
// Numerator FSM forward (single block) — R5's verified sum-renorm/lag-2 path.
// ---------------------------------------------------------------------------
template<int APT, int NST>
__device__ void fsm_forward_local(const float* __restrict__ rowbase, int L,
    const uint2* __restrict__ arcs_g,
    const float* __restrict__ initv, const float* __restrict__ finalv,
    float* __restrict__ res,
    float* elh, float* buf0, float* buf1, float* psum, float* red,
    unsigned* islot, float* sS)
{
    const int tid = threadIdx.x;
    uint2 arc[APT];
    #pragma unroll
    for (int k = 0; k < APT; ++k) arc[k] = arcs_g[tid * APT + k];

    if (tid < NST) { buf0[tid] = __expf(initv[tid]); buf1[tid] = 0.f; }
    #pragma unroll
    for (int i = 0; i < 4; ++i) elh[tid + 512 * i] = __expf(rowbase[tid + 512 * i]);
    if (tid == 0) { islot[0] = __float_as_uint(1.0f); islot[1] = __float_as_uint(1.0f); }
    float inv_prev = 1.f, inv_cur = 1.f, Sacc = 0.f, lastP = 1.f;
    __syncthreads();

    for (int t = 0; t < L; ++t) {
        float* bufR = (t & 1) ? buf1 : buf0;
        float* bufW = (t & 1) ? buf0 : buf1;
        const float inv = __uint_as_float(islot[t & 1]);
        float pf[4];
        {
            const int rn = (t + 1 < L) ? t + 1 : t;
            const float* nb = rowbase + (size_t)rn * CC;
            #pragma unroll
            for (int i = 0; i < 4; ++i) pf[i] = nb[tid + 512 * i];
        }
        float bb[APT], ef[APT];
        #pragma unroll
        for (int k = 0; k < APT; ++k) bb[k] = bufR[arc[k].x & 1023u];
        #pragma unroll
        for (int k = 0; k < APT; ++k) ef[k] = elh[(arc[k].x >> 10) & 2047u];
        float tot = 0.f, acc = 0.f;
        #pragma unroll
        for (int k = 0; k < APT; ++k) {
            const float p = bb[k] * __uint_as_float(arc[k].y) * ef[k];
            acc += p; tot += p;
            const unsigned nd = (k + 1 < APT) ? (arc[k + 1].x >> 21) : 0xffffffffu;
            if (nd != (arc[k].x >> 21)) {
                atomicAdd(&bufW[arc[k].x >> 21], acc * inv);
                acc = 0.f;
            }
        }
        psum[tid] = tot;
        if (t && (tid >> 6) == 7) {
            const int l = tid & 63;
            float r = red[l] + red[l + 64];
            #pragma unroll
            for (int off = 32; off > 0; off >>= 1) r += __shfl_xor(r, off);
            const float P = inv_prev * r;
            Sacc += __logf(P);
            lastP = P;
            const float newInv = 1.0f / P;
            inv_prev = inv_cur; inv_cur = newInv;
            if (l == 0) islot[(t + 1) & 1] = __float_as_uint(newInv);
        }
        __syncthreads();
        if (tid < NST) bufR[tid] = 0.f;
        if (tid < 128) {
            const float4 q = *(const float4*)&psum[tid * 4];
            red[tid] = q.x + q.y + q.z + q.w;
        }
        if (t + 1 < L) {
            #pragma unroll
            for (int i = 0; i < 4; ++i) elh[tid + 512 * i] = __expf(pf[i]);
        }
        __syncthreads();
    }

    const float* fb = (L & 1) ? buf1 : buf0;
    float v = 0.f;
    if (tid < NST) v = fb[tid] * __expf(finalv[tid]);
    psum[tid] = v;
    if (tid == 448) sS[0] = Sacc - __logf(lastP);
    __syncthreads();
    if (tid < 128) {
        const float4 q = *(const float4*)&psum[tid * 4];
        red[tid] = q.x + q.y + q.z + q.w;
    }
    __syncthreads();
    if (tid < 32) {
        const float4 q = *(const float4*)&red[tid * 4];
        psum[tid] = q.x + q.y + q.z + q.w;
    }
    __syncthreads();
    if (tid == 0) {
        float s2 = 0.f;
        for (int i = 0; i < 32; ++i) s2 += psum[i];
        *res = sS[0] + __logf(s2);
    }
}

// ---------------------------------------------------------------------------
// Denominator FSM forward split across 4 blocks (one dst-quarter each).
// Arcs are dst-sorted, so block q's quarter [256q,256q+256) receives ALL arcs
// of those states -> its nbl is complete; exchange = concatenation.
// Per-step protocol: [assemble beta(t-1) from xq, compute P(t-1)] -> barrier
// -> A(t): gathers + run-atomics into nbl, psum -> barrier -> publish quarter
// + partial T_q (double-buffered by t&1) -> barrier -> release-add cnt[f]
// -> tid0 acquire-spins for 4(t+1) -> barrier.
// ---------------------------------------------------------------------------
__device__ void fsm_forward_den_split(int f, int q,
    const float* __restrict__ rowbase, int L,
    const uint2* __restrict__ arcs_g, const unsigned* __restrict__ rowptr,
    const float* __restrict__ initv, const float* __restrict__ finalv,
    float* __restrict__ res,
    float* __restrict__ xq, float* __restrict__ xT, float* __restrict__ xF,
    unsigned* __restrict__ cnt,
    float* beta, float* elh, float* nbl, float* dpsum)
{
    const int tid = threadIdx.x;
    float* xq_f = xq + (size_t)f * 2048;   // [par][1024]
    float* xT_f = xT + (size_t)f * 8;      // [par][4]
    float* xF_f = xF + (size_t)f * 4;      // [4]
    unsigned* cnt_f = cnt + f;

    // ---- load this quarter's arcs (consecutive chunks preserve dst runs)
    const int r0 = (int)rowptr[q << 8];
    const int r1 = (int)rowptr[(q << 8) + 256];
    const int count = r1 - r0;
    int cpt = (count + 511) >> 9;
    if (cpt > APTD) cpt = APTD;            // statistically unreachable
    const int base = r0 + tid * cpt;
    int sidx[APTD], pidx[APTD], dloc[APTD];
    float wgt[APTD];
    #pragma unroll
    for (int k = 0; k < APTD; ++k) {
        const bool valid = (k < cpt) && (tid * cpt + k < count);
        uint2 a = valid ? arcs_g[base + k] : make_uint2(0u, 0u);
        sidx[k] = (int)(a.x & 1023u);
        pidx[k] = (int)((a.x >> 10) & 2047u);
        dloc[k] = valid ? (int)((a.x >> 21) - (unsigned)(q << 8)) : 0;
        wgt[k]  = valid ? __uint_as_float(a.y) : 0.f;
    }

    // ---- preamble: beta(=exp(init)) full vector, elh(0), nbl zero
    {
        const float2 iv = *(const float2*)&initv[2 * tid];
        float2 b2; b2.x = __expf(iv.x); b2.y = __expf(iv.y);
        *(float2*)&beta[2 * tid] = b2;
        const float4 p0 = *(const float4*)(rowbase + 4 * tid);
        float4 e4;
        e4.x = __expf(p0.x); e4.y = __expf(p0.y); e4.z = __expf(p0.z); e4.w = __expf(p0.w);
        *(float4*)&elh[4 * tid] = e4;
        if (tid < 64) *(float4*)&nbl[tid * 4] = make_float4(0.f, 0.f, 0.f, 0.f);
    }
    float S = 0.f, lastP = 1.f, ip = 1.f, ic = 1.f, in2 = 1.f;
    __syncthreads();

    for (int t = 0; t < L; ++t) {
        // ---- exchange-read phase (data of step t-1, parity (t-1)&1)
        if (t > 0) {
            const int par = (t - 1) & 1;
            const float* xqp = xq_f + par * 1024;
            const unsigned long long bv = aload_u64(xqp + 2 * tid);
            float2 b2; b2.x = u2f_lo(bv); b2.y = u2f_hi(bv);
            *(float2*)&beta[2 * tid] = b2;
            const float* xtp = xT_f + par * 4;
            const unsigned long long t01 = aload_u64(xtp);
            const unsigned long long t23 = aload_u64(xtp + 2);
            const float Tsum = u2f_lo(t01) + u2f_hi(t01) + u2f_lo(t23) + u2f_hi(t23);
            const float P = ip * Tsum;
            S += __logf(P); lastP = P; in2 = 1.0f / P;
            __syncthreads();
        }
        // ---- A phase
        float4 pf4;
        {
            const int rn = (t + 1 < L) ? (t + 1) : t;
            pf4 = *(const float4*)(rowbase + (size_t)rn * CC + 4 * tid);
        }
        float bbv[APTD], efv[APTD];
        #pragma unroll
        for (int k = 0; k < APTD; ++k) bbv[k] = beta[sidx[k]];
        #pragma unroll
        for (int k = 0; k < APTD; ++k) efv[k] = elh[pidx[k]];
        float tot = 0.f, acc = 0.f;
        #pragma unroll
        for (int k = 0; k < APTD; ++k) {
            const float pr = bbv[k] * wgt[k] * efv[k];
            acc += pr; tot += pr;
            const bool bnd = (k + 1 == APTD) || (dloc[k + 1] != dloc[k]);
            if (bnd) { atomicAdd(&nbl[dloc[k]], acc * ic); acc = 0.f; }
        }
        dpsum[tid] = tot;
        __syncthreads();
        // ---- publish phase (parity t&1)
        const int parw = t & 1;
        if (t + 1 < L) {
            if (tid < 64) {
                const float4 q4 = *(const float4*)&nbl[tid * 4];
                float* dq = xq_f + parw * 1024 + (q << 8) + tid * 4;
                astore_f(dq + 0, q4.x); astore_f(dq + 1, q4.y);
                astore_f(dq + 2, q4.z); astore_f(dq + 3, q4.w);
                *(float4*)&nbl[tid * 4] = make_float4(0.f, 0.f, 0.f, 0.f);
            } else if (tid < 128) {
                const int l = tid - 64;
                const float4 a = *(const float4*)&dpsum[l * 8];
                const float4 c = *(const float4*)&dpsum[l * 8 + 4];
                float r = a.x + a.y + a.z + a.w + c.x + c.y + c.z + c.w;
                #pragma unroll
                for (int off = 32; off > 0; off >>= 1) r += __shfl_xor(r, off);
                if (l == 0) astore_f(xT_f + parw * 4 + q, r);
            }
            float4 e4;
            e4.x = __expf(pf4.x); e4.y = __expf(pf4.y);
            e4.z = __expf(pf4.z); e4.w = __expf(pf4.w);
            *(float4*)&elh[4 * tid] = e4;
        } else {
            // last step: publish F_q = sum_{j in quarter} nbl[j] * e^{final_j}
            if (tid < 64) {
                const float4 q4 = *(const float4*)&nbl[tid * 4];
                const float4 f4 = *(const float4*)&finalv[(q << 8) + tid * 4];
                float r = q4.x * __expf(f4.x) + q4.y * __expf(f4.y)
                        + q4.z * __expf(f4.z) + q4.w * __expf(f4.w);
                #pragma unroll
                for (int off = 32; off > 0; off >>= 1) r += __shfl_xor(r, off);
                if (tid == 0) astore_f(xF_f + q, r);
            }
        }
        __syncthreads();
        if (tid == 0)
            __hip_atomic_fetch_add(cnt_f, 1u, __ATOMIC_RELEASE, __HIP_MEMORY_SCOPE_AGENT);
        if (t + 1 < L) {
            if (tid == 0) {
                const unsigned want = 4u * (unsigned)(t + 1);
                while (__hip_atomic_load(cnt_f, __ATOMIC_ACQUIRE,
                                         __HIP_MEMORY_SCOPE_AGENT) < want)
                    __builtin_amdgcn_s_sleep(8);
            }
            __syncthreads();
        }
        ip = ic; ic = in2;
    }

    // ---- final combine (block q==0 only)
    if (q == 0 && tid == 0) {
        const unsigned want = 4u * (unsigned)L;
        while (__hip_atomic_load(cnt_f, __ATOMIC_ACQUIRE,
                                 __HIP_MEMORY_SCOPE_AGENT) < want)
            __builtin_amdgcn_s_sleep(8);
        const unsigned long long f01 = aload_u64(xF_f);
        const unsigned long long f23 = aload_u64(xF_f + 2);
        const float F = u2f_lo(f01) + u2f_hi(f01) + u2f_lo(f23) + u2f_hi(f23);
        res[0] = S - __logf(lastP) + __logf(F);
    }
}

__global__ __launch_bounds__(512) void fwd_kernel(
    const float* __restrict__ est, const int* __restrict__ seqlen,
    const uint2* __restrict__ den_arcs, const unsigned* __restrict__ den_rowptr,
    const float* __restrict__ den_init, const float* __restrict__ den_final,
    const uint2* __restrict__ num_arcs,
    const float* __restrict__ num_init, const float* __restrict__ num_final,
    float* __restrict__ res,
    float* __restrict__ xq, float* __restrict__ xT, float* __restrict__ xF,
    unsigned* __restrict__ cnt)
{
    // den-split arrays
    __shared__ float beta[1024];
    __shared__ float delh[2048];
    __shared__ float nbl[256];
    __shared__ float dpsum[512];
    // num arrays (R5 path)
    __shared__ float nelh[2048];
    __shared__ float buf0[1024];
    __shared__ float buf1[1024];
    __shared__ float npsum[512];
    __shared__ float red[128];
    __shared__ unsigned islot[2];
    __shared__ float sS[1];

    const int bid = blockIdx.x;
    if (bid < 64) {
        // fsm f = bid & 15 (keeps a fsm's 4 blocks on one XCD if round-robin),
        // quarter q = bid >> 4
        const int f = bid & 15, q = bid >> 4;
        const int s = f >> 3, b = f & 7;
        const float* rowbase = est + (size_t)(b * SS + s) * TT * CC;
        const int L = seqlen[b * SS + s];
        fsm_forward_den_split(f, q, rowbase, L, den_arcs, den_rowptr,
                              den_init, den_final, &res[f],
                              xq, xT, xF, cnt, beta, delh, nbl, dpsum);
    } else {
        const int q2 = bid - 64;
        const int p = q2 >> 4, g = q2 & 15;
        const int s = g >> 3, b = g & 7;
        const int sp = p ? (1 - s) : s;
        const float* rowbase = est + (size_t)(b * SS + sp) * TT * CC;
        const int L = seqlen[b * SS + sp];
        fsm_forward_local<4, NN>(rowbase, L,
                                 num_arcs + (size_t)g * AN,
                                 num_init + (size_t)g * NN, num_final + (size_t)g * NN,
                                 &res[16 + p * 16 + g],
                                 nelh, buf0, buf1, npsum, red, islot, sS);
    }
}

// res layout: [0..15] den (s*8+b), [16..31] num perm0, [32..47] num perm1
__global__ void finalize_kernel(const float* __restrict__ res, float* __restrict__ out)
{
    if (threadIdx.x == 0 && blockIdx.x == 0) {
        float loss = 0.f;
        for (int b = 0; b < BB; ++b) {
            const float den = res[b] + res[8 + b];
            const float n0  = res[16 + b] + res[16 + 8 + b];
            const float n1  = res[32 + b] + res[32 + 8 + b];
            const float nm  = fminf(n0, n1);
            loss += -(nm - den);
        }
        out[0] = loss;
    }
}

extern "C" void kernel_launch(void* const* d_in, const int* in_sizes, int n_in,
                              void* d_out, int out_size, void* d_ws, size_t ws_size,
                              hipStream_t stream)
{
    const float* est       = (const float*)d_in[0];
    const int*   seqlen    = (const int*)  d_in[1];
    const int*   den_src   = (const int*)  d_in[2];
    const int*   den_dst   = (const int*)  d_in[3];
    const int*   den_pdf   = (const int*)  d_in[4];
    const float* den_w     = (const float*)d_in[5];
    const float* den_init  = (const float*)d_in[6];
    const float* den_final = (const float*)d_in[7];
    const int*   num_src   = (const int*)  d_in[8];
    const int*   num_dst   = (const int*)  d_in[9];
    const int*   num_pdf   = (const int*)  d_in[10];
    const float* num_w     = (const float*)d_in[11];
    const float* num_init  = (const float*)d_in[12];
    const float* num_final = (const float*)d_in[13];

    char* ws = (char*)d_ws;
    uint2*    den_arcs   = (uint2*)   (ws + 0);        // 131072
    uint2*    num_arcs   = (uint2*)   (ws + 131072);   // 262144 -> 393216
    unsigned* den_rowptr = (unsigned*)(ws + 393216);   // 4100   -> 397316
    float*    res        = (float*)   (ws + 397376);   // 192    -> 397568
    float*    xq         = (float*)   (ws + 397568);   // 131072 -> 528640
    float*    xT         = (float*)   (ws + 528640);   // 512    -> 529152
    float*    xF         = (float*)   (ws + 529152);   // 256    -> 529408
    unsigned* cnt        = (unsigned*)(ws + 529408);   // 64     -> 529472

    zero_sync_kernel<<<1, 64, 0, stream>>>(cnt);
    prep_kernel<<<1, 1024, 0, stream>>>(den_src, den_dst, den_pdf, den_w,
                                        den_arcs, den_rowptr, ND, AD);
    prep_kernel<<<16, 256, 0, stream>>>(num_src, num_dst, num_pdf, num_w,
                                        num_arcs, nullptr, NN, AN);

    fwd_kernel<<<96, 512, 0, stream>>>(est, seqlen,
                                       den_arcs, den_rowptr, den_init, den_final,
                                       num_arcs, num_init, num_final,
                                       res, xq, xT, xF, cnt);

    finalize_kernel<<<1, 64, 0, stream>>>(res, (float*)d_out);
}